// Round 19
// baseline (210.269 us; speedup 1.0000x reference)
//
#include <hip/hip_runtime.h>
#include <math.h>

// LMHT neuron forward — SOLVED SEMANTICS (R18 pre-timing absmax = 0.0):
//   v   = (v + x[t]) + Iz                       fp32, left-assoc
//   q   = clip(floor(fl32(v/s)), 0, 4)          canonical quantizer, computed
//         division-free via R5 midpoint compares (exact for any correctly-
//         rounded divide): q = #{m: (double)v >= sd*(m - h_m)},
//         h = {2^-25, 2^-24, 2^-23, 2^-23}
//   o   = fl32(q*s);  spike = o - Iz            (two-step; bf16-identical to
//                                                the fused alternative)
//   v   = fmaf(-q, s, v)                        THE KEY: single-rounded
//         v - q*s_exact — the npz reference generator (XLA/LLVM contract-
//         fast) fused mul(q,th)+sub(v,.) into an fma. Differs from
//         v - fl32(q*s) only at q=3 (fl32(3s) is 1 ulp above 3s exact).
//
// R18 failed ONLY the post-timing recheck: a single-element q0<->q4 flip
// (absmax 0.19970703 = the q0..q4 bf16 gap) after graph replay — not
// producible by this deterministic kernel from stable inputs (needs a
// >=0.15 perturbation of v). Treated as transient; this round resubmits
// the proven semantics with the carry as a TRUE fp32 fma (removes the f64
// double-rounding hazard of R18's emulation; otherwise byte-identical).

#pragma clang fp contract(off)

#define LMHT_T 4

__device__ __forceinline__ float lmht_step(float& v, float xt, float s, float Iz,
                                           double m1, double m2, double m3, double m4) {
#pragma clang fp contract(off)
    v = (v + xt) + Iz;                       // fp32, left-assoc as in the source
    double vd = (double)v;                   // exact
    int q = (vd >= m1) + (vd >= m2) + (vd >= m3) + (vd >= m4); // canonical quantizer
    float o = (float)q * s;                  // spike level fl32(q*s)
    v = fmaf(-(float)q, s, v);               // carry: single-rounded v - q*s (ref fma)
    return o - Iz;
}

__global__ __launch_bounds__(256) void lmht_kernel(
    const float4* __restrict__ x,      // (T, ND/4) fp32
    const float* __restrict__ scale_p, // scalar fp32
    const float* __restrict__ zp_p,    // scalar fp32
    float4* __restrict__ out,          // (T, ND/4) fp32
    long long nd4)
{
#pragma clang fp contract(off)
    const float s   = fminf(fmaxf(scale_p[0], 1e-4f), 1e4f);       // fp32 params
    const float rzp = fminf(fmaxf(rintf(zp_p[0]), 0.0f), 15.0f);   // np.round half-even
    const float Iz  = (rzp * 0.25f) * s;     // fl(0.75*s)
    const float v0  = s * 0.5f;              // exact

    const double sd = (double)s;
    const double m1 = sd * (1.0 - 0x1p-25);  // canonical floor(fl32(v/s)) midpoints
    const double m2 = sd * (2.0 - 0x1p-24);  // (division-path independent, R5 proof)
    const double m3 = sd * (3.0 - 0x1p-23);
    const double m4 = sd * (4.0 - 0x1p-23);

    long long idx    = (long long)blockIdx.x * blockDim.x + threadIdx.x;
    long long stride = (long long)gridDim.x * blockDim.x;

    for (long long i = idx; i < nd4; i += stride) {
        float4 v;
        v.x = v.y = v.z = v.w = v0;
        #pragma unroll
        for (int t = 0; t < LMHT_T; ++t) {
            float4 xt = x[(long long)t * nd4 + i];
            float4 o;
            o.x = lmht_step(v.x, xt.x, s, Iz, m1, m2, m3, m4);
            o.y = lmht_step(v.y, xt.y, s, Iz, m1, m2, m3, m4);
            o.z = lmht_step(v.z, xt.z, s, Iz, m1, m2, m3, m4);
            o.w = lmht_step(v.w, xt.w, s, Iz, m1, m2, m3, m4);
            out[(long long)t * nd4 + i] = o;
        }
    }
}

extern "C" void kernel_launch(void* const* d_in, const int* in_sizes, int n_in,
                              void* d_out, int out_size, void* d_ws, size_t ws_size,
                              hipStream_t stream) {
    const float* x     = (const float*)d_in[0];
    const float* scale = (const float*)d_in[1];
    const float* zp    = (const float*)d_in[2];
    float* out         = (float*)d_out;

    long long total = (long long)in_sizes[0];      // T * N * D
    long long nd    = total / LMHT_T;              // per-timestep plane
    long long nd4   = nd / 4;                      // float4 count

    const int block = 256;
    int grid = 4096;                               // grid-stride; ~8 iters/thread
    long long need = (nd4 + block - 1) / block;
    if (need < grid) grid = (int)need;

    lmht_kernel<<<grid, block, 0, stream>>>(
        (const float4*)x, scale, zp, (float4*)out, nd4);
}

// Round 21
// 203.264 us; speedup vs baseline: 1.0345x; 1.0345x over previous
//
#include <hip/hip_runtime.h>
#include <math.h>

// LMHT neuron forward — SOLVED SEMANTICS (R18/R19: absmax = 0.0, bit-exact):
//   v   = (v + x[t]) + Iz                      fp32, left-assoc
//   q   = clip(floor(fl32(v/s)), 0, 4)         canonical quantizer
//   o   = fl32(q*s);  spike = o - Iz
//   v   = fmaf(-q, s, v)                       single-rounded v - q*s (the npz
//                                              generator's XLA/LLVM fma fusion)
//
// R21 = R20's perf pass, compile-fixed (float4 struct members CAN bind to
// float&; ext_vector elements cannot — R20's only failure):
//  * Quantizer compares on the fp32 grid: v is always fp32, so
//    (double)v >= T_m  <=>  v >= c_m, c_m = smallest fp32 >= T_m (computed
//    once from the R5 midpoint doubles; division-path-independent proof
//    carries over). 4x v_cmp_ge_f32 instead of f64 cvt + 4x v_cmp_ge_f64.
//  * Nontemporal stores (output streamed, never re-read) to cut L2/L3
//    write-allocate pollution; loads stay cached.

#pragma clang fp contract(off)

#define LMHT_T 4

typedef float f32x4v __attribute__((ext_vector_type(4)));

__device__ __forceinline__ float nextupf_pos(float a) {
    return __uint_as_float(__float_as_uint(a) + 1u);   // a > 0, finite
}

// smallest fp32 >= T (T > 0)
__device__ __forceinline__ float ceil_f32(double T) {
    float f = (float)T;                    // RNE
    if ((double)f < T) f = nextupf_pos(f);
    return f;
}

__device__ __forceinline__ float lmht_step(float& v, float xt, float s, float Iz,
                                           float c1, float c2, float c3, float c4) {
#pragma clang fp contract(off)
    v = (v + xt) + Iz;                       // fp32, left-assoc as in the source
    int q = (v >= c1) + (v >= c2) + (v >= c3) + (v >= c4); // canonical quantizer
    float o = (float)q * s;                  // spike level fl32(q*s)
    v = fmaf(-(float)q, s, v);               // carry: single-rounded v - q*s (ref fma)
    return o - Iz;
}

__global__ __launch_bounds__(256) void lmht_kernel(
    const float4* __restrict__ x,      // (T, ND/4) fp32
    const float* __restrict__ scale_p, // scalar fp32
    const float* __restrict__ zp_p,    // scalar fp32
    float4* __restrict__ out,          // (T, ND/4) fp32
    long long nd4)
{
#pragma clang fp contract(off)
    const float s   = fminf(fmaxf(scale_p[0], 1e-4f), 1e4f);       // fp32 params
    const float rzp = fminf(fmaxf(rintf(zp_p[0]), 0.0f), 15.0f);   // np.round half-even
    const float Iz  = (rzp * 0.25f) * s;     // fl(0.75*s)
    const float v0  = s * 0.5f;              // exact

    const double sd = (double)s;
    // R5 midpoints (exact for any correctly-rounded divide), snapped UP to
    // the fp32 grid: v >= c_m  <=>  (double)v >= sd*(m - h_m) for fp32 v.
    const float c1 = ceil_f32(sd * (1.0 - 0x1p-25));
    const float c2 = ceil_f32(sd * (2.0 - 0x1p-24));
    const float c3 = ceil_f32(sd * (3.0 - 0x1p-23));
    const float c4 = ceil_f32(sd * (4.0 - 0x1p-23));

    long long idx    = (long long)blockIdx.x * blockDim.x + threadIdx.x;
    long long stride = (long long)gridDim.x * blockDim.x;

    for (long long i = idx; i < nd4; i += stride) {
        float4 v;
        v.x = v.y = v.z = v.w = v0;
        #pragma unroll
        for (int t = 0; t < LMHT_T; ++t) {
            float4 xt = x[(long long)t * nd4 + i];
            float4 o;
            o.x = lmht_step(v.x, xt.x, s, Iz, c1, c2, c3, c4);
            o.y = lmht_step(v.y, xt.y, s, Iz, c1, c2, c3, c4);
            o.z = lmht_step(v.z, xt.z, s, Iz, c1, c2, c3, c4);
            o.w = lmht_step(v.w, xt.w, s, Iz, c1, c2, c3, c4);
            f32x4v ov = {o.x, o.y, o.z, o.w};
            __builtin_nontemporal_store(ov, (f32x4v*)&out[(long long)t * nd4 + i]);
        }
    }
}

extern "C" void kernel_launch(void* const* d_in, const int* in_sizes, int n_in,
                              void* d_out, int out_size, void* d_ws, size_t ws_size,
                              hipStream_t stream) {
    const float* x     = (const float*)d_in[0];
    const float* scale = (const float*)d_in[1];
    const float* zp    = (const float*)d_in[2];
    float* out         = (float*)d_out;

    long long total = (long long)in_sizes[0];      // T * N * D
    long long nd    = total / LMHT_T;              // per-timestep plane
    long long nd4   = nd / 4;                      // float4 count

    const int block = 256;
    int grid = 4096;                               // grid-stride; ~8 iters/thread
    long long need = (nd4 + block - 1) / block;
    if (need < grid) grid = (int)need;

    lmht_kernel<<<grid, block, 0, stream>>>(
        (const float4*)x, scale, zp, (float4*)out, nd4);
}

// Round 22
// 196.932 us; speedup vs baseline: 1.0677x; 1.0322x over previous
//
#include <hip/hip_runtime.h>
#include <math.h>

// LMHT neuron forward — SOLVED SEMANTICS (R18/R19/R21: absmax = 0.0):
//   v   = (v + x[t]) + Iz                      fp32, left-assoc
//   q   = clip(floor(fl32(v/s)), 0, 4)         canonical quantizer (fp32-grid
//                                              compares, R5-proof-derived)
//   o   = fl32(q*s);  spike = o - Iz
//   v   = fmaf(-q, s, v)                       single-rounded v - q*s (the npz
//                                              generator's XLA/LLVM fma fusion)
//
// R22 = last perf experiment: NONTEMPORAL LOADS as well as stores.
// R21 sits at 5.28 TB/s (84% of the 6.29 TB/s float4-copy ceiling); the
// input is 537 MB streamed once (zero reuse possible, >> 256 MB L3), so
// L2/L3 allocation on the read stream is pure overhead competing with the
// write stream. If this is the residual cost: ~190 us. If flat: the
// 8-stream DRAM mix is the roofline; stop.

#pragma clang fp contract(off)

#define LMHT_T 4

typedef float f32x4v __attribute__((ext_vector_type(4)));

__device__ __forceinline__ float nextupf_pos(float a) {
    return __uint_as_float(__float_as_uint(a) + 1u);   // a > 0, finite
}

// smallest fp32 >= T (T > 0)
__device__ __forceinline__ float ceil_f32(double T) {
    float f = (float)T;                    // RNE
    if ((double)f < T) f = nextupf_pos(f);
    return f;
}

__device__ __forceinline__ float lmht_step(float& v, float xt, float s, float Iz,
                                           float c1, float c2, float c3, float c4) {
#pragma clang fp contract(off)
    v = (v + xt) + Iz;                       // fp32, left-assoc as in the source
    int q = (v >= c1) + (v >= c2) + (v >= c3) + (v >= c4); // canonical quantizer
    float o = (float)q * s;                  // spike level fl32(q*s)
    v = fmaf(-(float)q, s, v);               // carry: single-rounded v - q*s (ref fma)
    return o - Iz;
}

__global__ __launch_bounds__(256) void lmht_kernel(
    const float4* __restrict__ x,      // (T, ND/4) fp32
    const float* __restrict__ scale_p, // scalar fp32
    const float* __restrict__ zp_p,    // scalar fp32
    float4* __restrict__ out,          // (T, ND/4) fp32
    long long nd4)
{
#pragma clang fp contract(off)
    const float s   = fminf(fmaxf(scale_p[0], 1e-4f), 1e4f);       // fp32 params
    const float rzp = fminf(fmaxf(rintf(zp_p[0]), 0.0f), 15.0f);   // np.round half-even
    const float Iz  = (rzp * 0.25f) * s;     // fl(0.75*s)
    const float v0  = s * 0.5f;              // exact

    const double sd = (double)s;
    // R5 midpoints (exact for any correctly-rounded divide), snapped UP to
    // the fp32 grid: v >= c_m  <=>  (double)v >= sd*(m - h_m) for fp32 v.
    const float c1 = ceil_f32(sd * (1.0 - 0x1p-25));
    const float c2 = ceil_f32(sd * (2.0 - 0x1p-24));
    const float c3 = ceil_f32(sd * (3.0 - 0x1p-23));
    const float c4 = ceil_f32(sd * (4.0 - 0x1p-23));

    long long idx    = (long long)blockIdx.x * blockDim.x + threadIdx.x;
    long long stride = (long long)gridDim.x * blockDim.x;

    for (long long i = idx; i < nd4; i += stride) {
        float v0_ = v0, v1_ = v0, v2_ = v0, v3_ = v0;
        #pragma unroll
        for (int t = 0; t < LMHT_T; ++t) {
            f32x4v xt = __builtin_nontemporal_load(
                (const f32x4v*)&x[(long long)t * nd4 + i]);
            f32x4v ov;
            ov.x = lmht_step(v0_, xt.x, s, Iz, c1, c2, c3, c4);
            ov.y = lmht_step(v1_, xt.y, s, Iz, c1, c2, c3, c4);
            ov.z = lmht_step(v2_, xt.z, s, Iz, c1, c2, c3, c4);
            ov.w = lmht_step(v3_, xt.w, s, Iz, c1, c2, c3, c4);
            __builtin_nontemporal_store(ov, (f32x4v*)&out[(long long)t * nd4 + i]);
        }
    }
}

extern "C" void kernel_launch(void* const* d_in, const int* in_sizes, int n_in,
                              void* d_out, int out_size, void* d_ws, size_t ws_size,
                              hipStream_t stream) {
    const float* x     = (const float*)d_in[0];
    const float* scale = (const float*)d_in[1];
    const float* zp    = (const float*)d_in[2];
    float* out         = (float*)d_out;

    long long total = (long long)in_sizes[0];      // T * N * D
    long long nd    = total / LMHT_T;              // per-timestep plane
    long long nd4   = nd / 4;                      // float4 count

    const int block = 256;
    int grid = 4096;                               // grid-stride; ~8 iters/thread
    long long need = (nd4 + block - 1) / block;
    if (need < grid) grid = (int)need;

    lmht_kernel<<<grid, block, 0, stream>>>(
        (const float4*)x, scale, zp, (float4*)out, nd4);
}